// Round 2
// baseline (165.833 us; speedup 1.0000x reference)
//
#include <hip/hip_runtime.h>

// out[i] = prod_j sigmoid((ub[j] - logit(bc[idx[i][j]])) / (ub[j] - lb[j] + 1e-4))
//
// HBM floor: 96 MiB idx read + 32 MiB out write ~= 20 us @ 6.3 TB/s.
// R1 (162 us) lesson: per-thread idx4[3v..3v+2] loads put consecutive lanes
// 48 B apart -> each wave dwordx4 splits into ~48 transactions (3-4x TA cost).
// R2: wave loads its contiguous 3072-B idx span with lane-contiguous int4
// loads (perfectly coalesced), transposes to per-thread row-groups through a
// wave-private LDS stage (no barrier needed: same-wave, in-order DS pipe).
// Sigmoid is a 3x1000 LDS LUT (transcendentals are O(bins), not O(rows)).
// Persistent grid: 2048 blocks, 4 grid-stride iterations/thread.

#define EPS 1e-4f
#define TPB 256
#define NBLK 2048
#define BINCAP 1024

__global__ __launch_bounds__(TPB) void pm_kernel(
    const float* __restrict__ bc,      // [nbins]
    const int*   __restrict__ idx,     // [ndiffs, 3] int32
    const float* __restrict__ lo,      // [3]
    const float* __restrict__ hi,      // [3]
    float*       __restrict__ out,     // [ndiffs]
    int nbins, int ndiffs)
{
    __shared__ float tab[3][BINCAP];   // 12 KB sigmoid LUT
    __shared__ int   stage[TPB * 12];  // 12 KB: 48 B/thread, wave-private 3 KB regions

    // Effective bounds (reference swaps if lb > ub)
    const float lb0 = fminf(lo[0], hi[0]), ub0 = fmaxf(lo[0], hi[0]);
    const float lb1 = fminf(lo[1], hi[1]), ub1 = fmaxf(lo[1], hi[1]);
    const float lb2 = fminf(lo[2], hi[2]), ub2 = fmaxf(lo[2], hi[2]);
    const float r0 = 1.0f / (ub0 - lb0 + EPS);
    const float r1 = 1.0f / (ub1 - lb1 + EPS);
    const float r2 = 1.0f / (ub2 - lb2 + EPS);

    for (int b = threadIdx.x; b < nbins; b += TPB) {
        const float t = bc[b];
        const float g = __logf(t / (1.0f - t));          // logit
        tab[0][b] = 1.0f / (1.0f + __expf((g - ub0) * r0));
        tab[1][b] = 1.0f / (1.0f + __expf((g - ub1) * r1));
        tab[2][b] = 1.0f / (1.0f + __expf((g - ub2) * r2));
    }
    __syncthreads();

    const int tid    = blockIdx.x * TPB + threadIdx.x;
    const int stride = gridDim.x * TPB;
    const int lane   = threadIdx.x & 63;
    const int nvec   = ndiffs >> 2;                      // float4 groups

    const int4* __restrict__ idx4 = (const int4*)idx;
    float4*     __restrict__ out4 = (float4*)out;

    int4*      s4 = (int4*)(stage + (threadIdx.x >> 6) * (64 * 12));
    const int* my = (const int*)s4 + 12 * lane;          // this thread's 12 ints

    for (int v = tid; v - lane < nvec; v += stride) {
        const int wbase = v - lane;                      // wave-uniform
        if (wbase + 64 <= nvec) {
            // Wave's span = int4[3*wbase .. 3*wbase+192): 3 coalesced loads
            const int b3 = 3 * wbase;
            const int4 q0 = idx4[b3 + lane];             // lane stride 16 B
            const int4 q1 = idx4[b3 + 64 + lane];
            const int4 q2 = idx4[b3 + 128 + lane];
            s4[lane]       = q0;                         // contiguous LDS image
            s4[lane + 64]  = q1;
            s4[lane + 128] = q2;
            // same-wave exchange: DS pipe is in-order, no barrier needed
            float4 r;
            r.x = tab[0][my[0]] * tab[1][my[1]]  * tab[2][my[2]];
            r.y = tab[0][my[3]] * tab[1][my[4]]  * tab[2][my[5]];
            r.z = tab[0][my[6]] * tab[1][my[7]]  * tab[2][my[8]];
            r.w = tab[0][my[9]] * tab[1][my[10]] * tab[2][my[11]];
            out4[v] = r;
        } else if (v < nvec) {
            // partial-wave fallback (not hit at 8388608): direct loads
            const int4 a = idx4[3*v], b = idx4[3*v+1], c = idx4[3*v+2];
            float4 r;
            r.x = tab[0][a.x] * tab[1][a.y] * tab[2][a.z];
            r.y = tab[0][a.w] * tab[1][b.x] * tab[2][b.y];
            r.z = tab[0][b.z] * tab[1][b.w] * tab[2][c.x];
            r.w = tab[0][c.y] * tab[1][c.z] * tab[2][c.w];
            out4[v] = r;
        }
    }

    // Row tail (ndiffs % 4) — none for 8388608, kept for generality
    for (int i = (nvec << 2) + tid; i < ndiffs; i += stride) {
        out[i] = tab[0][idx[3*i]] * tab[1][idx[3*i+1]] * tab[2][idx[3*i+2]];
    }
}

extern "C" void kernel_launch(void* const* d_in, const int* in_sizes, int n_in,
                              void* d_out, int out_size, void* d_ws, size_t ws_size,
                              hipStream_t stream)
{
    const float* bc  = (const float*)d_in[0];
    const int*   idx = (const int*)  d_in[1];
    const float* lo  = (const float*)d_in[2];
    const float* hi  = (const float*)d_in[3];
    float*       out = (float*)d_out;

    const int nbins  = in_sizes[0];
    const int ndiffs = out_size;

    pm_kernel<<<NBLK, TPB, 0, stream>>>(bc, idx, lo, hi, out, nbins, ndiffs);
}